// Round 9
// baseline (365.758 us; speedup 1.0000x reference)
//
#include <hip/hip_runtime.h>

#define NN 100000
#define NE 1600000

#define BSH 9                                  // 512 nodes/bucket
#define NBUCK2 ((NN + 511) / 512)              // 196 coarse buckets
#define CHUNK 8192                             // edges per partition block
#define NCHK ((NE + CHUNK - 1) / CHUNK)        // 196 chunks
#define L2T (NBUCK2 * NCHK)                    // 38416
#define NSTRIP (NN / 32)                       // 3125 exact

using bf16x8 = __attribute__((ext_vector_type(8))) short;
using f32x16 = __attribute__((ext_vector_type(16))) float;

// ---- bf16 helpers (RNE) ----
__device__ __forceinline__ unsigned short f2bf(float f) {
    unsigned u = __float_as_uint(f);
    u += 0x7FFFu + ((u >> 16) & 1u);
    return (unsigned short)(u >> 16);
}
__device__ __forceinline__ float bf2f(unsigned short h) {
    return __uint_as_float(((unsigned)h) << 16);
}

// ---------------- per-chunk bucket histogram (LDS only) ----------------
__global__ __launch_bounds__(256) void hist2_kernel(const int* __restrict__ dst,
                                                    int* __restrict__ histm) {
    __shared__ int lh[256];
    int blk = blockIdx.x, tid = threadIdx.x;
    lh[tid] = 0;
    __syncthreads();
    int base = blk * CHUNK;
#pragma unroll
    for (int t = 0; t < CHUNK / 256; t++) {
        int e = base + t * 256 + tid;
        if (e < NE) atomicAdd(&lh[dst[e] >> BSH], 1);
    }
    __syncthreads();
    if (tid < NBUCK2) histm[tid * NCHK + blk] = lh[tid];   // bucket-major
}

// ---------------- single-block exclusive scan over histm (L2T ints) ----------------
__global__ __launch_bounds__(1024) void scan_histm_kernel(int* __restrict__ data) {
    __shared__ int s[1024];
    const int PER = (L2T + 1023) / 1024;        // 38
    int tid = threadIdx.x;
    int lo = tid * PER;
    int hi = lo + PER; if (hi > L2T) hi = L2T;
    int sum = 0;
    for (int i = lo; i < hi; i++) sum += data[i];
    s[tid] = sum;
    __syncthreads();
    for (int off = 1; off < 1024; off <<= 1) {
        int val = (tid >= off) ? s[tid - off] : 0;
        __syncthreads();
        s[tid] += val;
        __syncthreads();
    }
    int run = s[tid] - sum;                     // exclusive prefix of this span
    for (int i = lo; i < hi; i++) {
        int d = data[i];
        data[i] = run;
        run += d;
    }
}

// ---------------- coarse scatter, LDS counting-sort per chunk ----------------
// Instead of 1.6M random 4B global writes (each a full cache line), sort the
// chunk's edges by bucket in LDS (count -> scan -> place), then stream out:
// consecutive threads write consecutive addresses within each bucket's ~168B
// run. Write traffic ~5-8x lower. 44KB LDS -> 3 blk/CU.
__global__ __launch_bounds__(256) void scatter2_kernel(const int* __restrict__ src,
                                                       const int* __restrict__ dst,
                                                       const int* __restrict__ histm,
                                                       int* __restrict__ tmp) {
    __shared__ int staged[CHUNK];               // 32 KB, bucket-sorted values
    __shared__ unsigned char stb[CHUNK];        // 8 KB, bucket id per slot
    __shared__ int cnt[NBUCK2];
    __shared__ int loc[NBUCK2];                 // local exclusive scan (stable)
    __shared__ int cur[NBUCK2];                 // placement cursors
    __shared__ int segb[NBUCK2];                // global segment bases
    __shared__ int s[256];
    int blk = blockIdx.x, tid = threadIdx.x;
    int base = blk * CHUNK;
    int n = NE - base; if (n > CHUNK) n = CHUNK;

    for (int i = tid; i < NBUCK2; i += 256) cnt[i] = 0;
    __syncthreads();
    // pass 1: count buckets
    for (int j = tid; j < n; j += 256)
        atomicAdd(&cnt[dst[base + j] >> BSH], 1);
    __syncthreads();
    // 196-wide exclusive scan via 256-wide Hillis-Steele
    int c = (tid < NBUCK2) ? cnt[tid] : 0;
    s[tid] = c;
    __syncthreads();
    for (int off = 1; off < 256; off <<= 1) {
        int val = (tid >= off) ? s[tid - off] : 0;
        __syncthreads();
        s[tid] += val;
        __syncthreads();
    }
    if (tid < NBUCK2) {
        int ex = s[tid] - c;
        loc[tid] = ex;
        cur[tid] = ex;
        segb[tid] = histm[tid * NCHK + blk];    // global base of (bucket, chunk)
    }
    __syncthreads();
    // pass 2: rank + place into sorted LDS staging
    for (int j = tid; j < n; j += 256) {
        int d = dst[base + j];
        int b = d >> BSH;
        int v = src[base + j] | ((d & 511) << 17);   // src < 2^17
        int r = atomicAdd(&cur[b], 1);
        staged[r] = v;
        stb[r] = (unsigned char)b;
    }
    __syncthreads();
    // pass 3: streaming write-out (coalesced within bucket runs)
    for (int j = tid; j < n; j += 256) {
        int b = stb[j];
        tmp[segb[b] + (j - loc[b])] = staged[j];
    }
}

// ---------------- fused count + scan + place per bucket ----------------
__global__ __launch_bounds__(256) void count_place_kernel(const int* __restrict__ histm,
                                                          const int* __restrict__ tmp,
                                                          int* __restrict__ rowptr,
                                                          int* __restrict__ esrc) {
    __shared__ int cnt[512];   // counts, then cursors
    __shared__ int s[256];
    int b = blockIdx.x, tid = threadIdx.x;
    int beg = histm[b * NCHK];
    int end = (b == NBUCK2 - 1) ? NE : histm[(b + 1) * NCHK];

    cnt[tid] = 0; cnt[tid + 256] = 0;
    __syncthreads();
    for (int e = beg + tid; e < end; e += 256)
        atomicAdd(&cnt[tmp[e] >> 17], 1);               // LDS atomic
    __syncthreads();

    int c0 = cnt[2 * tid], c1 = cnt[2 * tid + 1];
    int sum = c0 + c1;
    s[tid] = sum;
    __syncthreads();
    for (int off = 1; off < 256; off <<= 1) {
        int val = (tid >= off) ? s[tid - off] : 0;
        __syncthreads();
        s[tid] += val;
        __syncthreads();
    }
    int o0 = beg + s[tid] - sum;                        // exclusive
    int o1 = o0 + c0;
    cnt[2 * tid] = o0;                                  // cursors
    cnt[2 * tid + 1] = o1;
    int node0 = (b << BSH) + 2 * tid;
    if (node0 < NN)     rowptr[node0]     = o0;
    if (node0 + 1 < NN) rowptr[node0 + 1] = o1;
    if (b == 0 && tid == 0) rowptr[NN] = NE;
    __syncthreads();

    for (int e = beg + tid; e < end; e += 256) {
        int v = tmp[e];
        int p = atomicAdd(&cnt[v >> 17], 1);            // LDS atomic
        esrc[p] = v & 0x1FFFF;
    }
}

// ---------------- fp32 -> bf16 convert ----------------
__global__ __launch_bounds__(256) void cvt_kernel(const float* __restrict__ in,
                                                  unsigned short* __restrict__ out, int n4) {
    int i = blockIdx.x * 256 + threadIdx.x;
    if (i < n4) {
        float4 f = ((const float4*)in)[i];
        ((ushort4*)out)[i] = make_ushort4(f2bf(f.x), f2bf(f.y), f2bf(f.z), f2bf(f.w));
    }
}

// ---------------- all 4 weight planes in one dispatch ----------------
__global__ __launch_bounds__(256) void cvtw_kernel(const float* __restrict__ W1l,
                                                   const float* __restrict__ W1r,
                                                   const float* __restrict__ W2l,
                                                   const float* __restrict__ W2r,
                                                   unsigned short* __restrict__ W1lb,
                                                   unsigned short* __restrict__ W1rb,
                                                   unsigned short* __restrict__ W2lb,
                                                   unsigned short* __restrict__ W2rb) {
    const int N1 = 128 * 64 / 4, N2 = 128 * 128 / 4;
    int j = blockIdx.x * 256 + threadIdx.x;
    const float* in; unsigned short* out;
    if (j < N1)              { in = W1l; out = W1lb; }
    else if ((j -= N1) < N1) { in = W1r; out = W1rb; }
    else if ((j -= N1) < N2) { in = W2l; out = W2lb; }
    else                     { j -= N2; if (j >= N2) return; in = W2r; out = W2rb; }
    float4 f = ((const float4*)in)[j];
    ((ushort4*)out)[j] = make_ushort4(f2bf(f.x), f2bf(f.y), f2bf(f.z), f2bf(f.w));
}

// ---------------- bf16 mean-aggregate, K=64 ----------------
__global__ __launch_bounds__(256) void agg64_kernel(const unsigned short* __restrict__ feat,
                                                    const int* __restrict__ rowptr,
                                                    const int* __restrict__ esrc,
                                                    unsigned short* __restrict__ agg) {
    int node = blockIdx.x * 4 + (threadIdx.x >> 6);
    int lane = threadIdx.x & 63;
    int es = lane >> 3;            // edge slot 0..7
    int fi = lane & 7;             // feature block (8 bf16)
    int beg = rowptr[node], end = rowptr[node + 1];

    float ax[8];
#pragma unroll
    for (int i = 0; i < 8; i++) ax[i] = 0.0f;

    int e = beg;
    for (; e + 15 < end; e += 16) {
        int sA = esrc[e + es];
        int sB = esrc[e + 8 + es];
        bf16x8 uA = *(const bf16x8*)(feat + (size_t)sA * 64 + fi * 8);
        bf16x8 uB = *(const bf16x8*)(feat + (size_t)sB * 64 + fi * 8);
#pragma unroll
        for (int i = 0; i < 8; i++)
            ax[i] += bf2f((unsigned short)uA[i]) + bf2f((unsigned short)uB[i]);
    }
    if (e + 7 < end) {
        int s = esrc[e + es];
        bf16x8 u = *(const bf16x8*)(feat + (size_t)s * 64 + fi * 8);
#pragma unroll
        for (int i = 0; i < 8; i++) ax[i] += bf2f((unsigned short)u[i]);
        e += 8;
    }
    if (es < end - e) {
        int s = esrc[e + es];
        bf16x8 u = *(const bf16x8*)(feat + (size_t)s * 64 + fi * 8);
#pragma unroll
        for (int i = 0; i < 8; i++) ax[i] += bf2f((unsigned short)u[i]);
    }

#pragma unroll
    for (int i = 0; i < 8; i++) {
        ax[i] += __shfl_xor(ax[i], 8);
        ax[i] += __shfl_xor(ax[i], 16);
        ax[i] += __shfl_xor(ax[i], 32);
    }
    if (es == 0) {
        float inv = 1.0f / fmaxf((float)(end - beg), 1.0f);
        bf16x8 o;
#pragma unroll
        for (int i = 0; i < 8; i++) o[i] = (short)f2bf(ax[i] * inv);
        *(bf16x8*)(agg + (size_t)node * 64 + fi * 8) = o;
    }
}

// ---------------- bf16 mean-aggregate, K=128 ----------------
__global__ __launch_bounds__(256) void agg128_kernel(const unsigned short* __restrict__ feat,
                                                     const int* __restrict__ rowptr,
                                                     const int* __restrict__ esrc,
                                                     unsigned short* __restrict__ agg) {
    int node = blockIdx.x * 4 + (threadIdx.x >> 6);
    int lane = threadIdx.x & 63;
    int es = lane >> 4;            // edge slot 0..3
    int fi = lane & 15;            // feature block (8 bf16)
    int beg = rowptr[node], end = rowptr[node + 1];

    float ax[8];
#pragma unroll
    for (int i = 0; i < 8; i++) ax[i] = 0.0f;

    int e = beg;
    for (; e + 15 < end; e += 16) {
        int s0 = esrc[e + es];
        int s1 = esrc[e + 4 + es];
        int s2 = esrc[e + 8 + es];
        int s3 = esrc[e + 12 + es];
        bf16x8 u0 = *(const bf16x8*)(feat + (size_t)s0 * 128 + fi * 8);
        bf16x8 u1 = *(const bf16x8*)(feat + (size_t)s1 * 128 + fi * 8);
        bf16x8 u2 = *(const bf16x8*)(feat + (size_t)s2 * 128 + fi * 8);
        bf16x8 u3 = *(const bf16x8*)(feat + (size_t)s3 * 128 + fi * 8);
#pragma unroll
        for (int i = 0; i < 8; i++)
            ax[i] += (bf2f((unsigned short)u0[i]) + bf2f((unsigned short)u1[i])) +
                     (bf2f((unsigned short)u2[i]) + bf2f((unsigned short)u3[i]));
    }
    for (; e + 3 < end; e += 4) {
        int s = esrc[e + es];
        bf16x8 u = *(const bf16x8*)(feat + (size_t)s * 128 + fi * 8);
#pragma unroll
        for (int i = 0; i < 8; i++) ax[i] += bf2f((unsigned short)u[i]);
    }
    if (es < end - e) {
        int s = esrc[e + es];
        bf16x8 u = *(const bf16x8*)(feat + (size_t)s * 128 + fi * 8);
#pragma unroll
        for (int i = 0; i < 8; i++) ax[i] += bf2f((unsigned short)u[i]);
    }

#pragma unroll
    for (int i = 0; i < 8; i++) {
        ax[i] += __shfl_xor(ax[i], 16);
        ax[i] += __shfl_xor(ax[i], 32);
    }
    if (es == 0) {
        float inv = 1.0f / fmaxf((float)(end - beg), 1.0f);
        bf16x8 o;
#pragma unroll
        for (int i = 0; i < 8; i++) o[i] = (short)f2bf(ax[i] * inv);
        *(bf16x8*)(agg + (size_t)node * 128 + fi * 8) = o;
    }
}

// ---------------- MFMA GEMM: out[n,0:128] = A1@Wa.T + A2@Wb.T + bias ----------------
template <int K, bool RELU, bool OUTBF>
__global__ __launch_bounds__(256) void gemm_mfma_kernel(
    const unsigned short* __restrict__ A1,
    const unsigned short* __restrict__ A2,
    const unsigned short* __restrict__ Wa,
    const unsigned short* __restrict__ Wb,
    const float* __restrict__ bias,
    void* __restrict__ outv) {
    int strip = blockIdx.x * 4 + (threadIdx.x >> 6);
    if (strip >= NSTRIP) return;
    const int lane = threadIdx.x & 63;
    const int m = lane & 31;
    const int half = lane >> 5;
    const int base = strip * 32;

    f32x16 acc[4];
#pragma unroll
    for (int nb = 0; nb < 4; ++nb)
#pragma unroll
        for (int r = 0; r < 16; ++r) acc[nb][r] = 0.0f;

    const unsigned short* ar1 = A1 + (size_t)(base + m) * K + half * 8;
    const unsigned short* ar2 = A2 + (size_t)(base + m) * K + half * 8;
#pragma unroll
    for (int kc = 0; kc < K; kc += 16) {
        bf16x8 a = *(const bf16x8*)(ar1 + kc);
#pragma unroll
        for (int nb = 0; nb < 4; ++nb) {
            bf16x8 b = *(const bf16x8*)(Wa + (size_t)(nb * 32 + m) * K + kc + half * 8);
            acc[nb] = __builtin_amdgcn_mfma_f32_32x32x16_bf16(a, b, acc[nb], 0, 0, 0);
        }
    }
#pragma unroll
    for (int kc = 0; kc < K; kc += 16) {
        bf16x8 a = *(const bf16x8*)(ar2 + kc);
#pragma unroll
        for (int nb = 0; nb < 4; ++nb) {
            bf16x8 b = *(const bf16x8*)(Wb + (size_t)(nb * 32 + m) * K + kc + half * 8);
            acc[nb] = __builtin_amdgcn_mfma_f32_32x32x16_bf16(a, b, acc[nb], 0, 0, 0);
        }
    }

#pragma unroll
    for (int nb = 0; nb < 4; ++nb) {
        int j = nb * 32 + m;
        float bz = bias[j];
#pragma unroll
        for (int r = 0; r < 16; ++r) {
            int row = (r & 3) + 8 * (r >> 2) + 4 * half;
            float v = acc[nb][r] + bz;
            if (RELU) v = fmaxf(v, 0.0f);
            size_t idx = (size_t)(base + row) * 128 + j;
            if (OUTBF) ((unsigned short*)outv)[idx] = f2bf(v);
            else       ((float*)outv)[idx] = v;
        }
    }
}

extern "C" void kernel_launch(void* const* d_in, const int* in_sizes, int n_in,
                              void* d_out, int out_size, void* d_ws, size_t ws_size,
                              hipStream_t stream) {
    const float* x   = (const float*)d_in[0];
    const int*   ei  = (const int*)d_in[1];
    const float* W1l = (const float*)d_in[2];
    const float* W1r = (const float*)d_in[3];
    const float* b1  = (const float*)d_in[4];
    const float* W2l = (const float*)d_in[5];
    const float* W2r = (const float*)d_in[6];
    const float* b2  = (const float*)d_in[7];
    float* out = (float*)d_out;

    const int* src = ei;        // edge_index[0]
    const int* dst = ei + NE;   // edge_index[1]

    // ---- workspace layout ----
    char* ws = (char*)d_ws;
    int* rowptr = (int*)ws;                                  // [0, 401408)
    int* esrc   = (int*)(ws + 401408);                       // NE ints
    unsigned short* aggB = (unsigned short*)(ws + 6803456);  // NN*128 bf16 (25.6 MB)
    unsigned short* xb   = aggB + (size_t)NN * 64;           // NN*64 bf16, aggB upper half
    char* E = ws + 32403456;                                 // 25.6 MB region
    unsigned short* hb = (unsigned short*)E;                 // NN*128 bf16
    int* tmp   = (int*)E;                                    // NE ints (transient)
    int* histm = (int*)(E + 6400000);                        // L2T ints (transient)
    // W bf16 copies:
    unsigned short* W1lb = (unsigned short*)d_out;           // 128*64 bf16 (16 KB)
    unsigned short* W1rb = W1lb + 128 * 64;
    unsigned short* W2lb;
    unsigned short* W2rb;
    {
        unsigned short* wbase = (unsigned short*)(E + 6400000 + L2T * 4 + 256); // after histm
        W2lb = wbase;                                        // 32 KB (clobbered by hb later; re-converted)
        W2rb = wbase + 128 * 128;                            // 32 KB
    }

    const int GB  = (NSTRIP + 3) / 4;                        // 782 gemm blocks

    // ---- build CSR (edge list sorted by dst); no global atomics ----
    hist2_kernel<<<NCHK, 256, 0, stream>>>(dst, histm);
    scan_histm_kernel<<<1, 1024, 0, stream>>>(histm);
    scatter2_kernel<<<NCHK, 256, 0, stream>>>(src, dst, histm, tmp);
    count_place_kernel<<<NBUCK2, 256, 0, stream>>>(histm, tmp, rowptr, esrc);

    // ---- bf16 planes ----
    cvt_kernel<<<(NN * 64 / 4 + 255) / 256, 256, 0, stream>>>(x, xb, NN * 64 / 4);
    cvtw_kernel<<<48, 256, 0, stream>>>(W1l, W1r, W2l, W2r, W1lb, W1rb, W2lb, W2rb);

    // ---- layer 1: hb = bf16(relu(mean(agg) @ W1l.T + x @ W1r.T + b1)) ----
    agg64_kernel<<<NN / 4, 256, 0, stream>>>(xb, rowptr, esrc, aggB);
    gemm_mfma_kernel<64, true, true><<<GB, 256, 0, stream>>>(aggB, xb, W1lb, W1rb, b1, hb);
    // NOTE: hb (at E) overwrites tmp (dead) AND the early W2 planes -> W2
    // re-converted below into the rowptr region once rowptr/esrc are dead.

    // ---- layer 2: out = mean(agg2) @ W2l.T + hb @ W2r.T + b2 ----
    agg128_kernel<<<NN / 4, 256, 0, stream>>>(hb, rowptr, esrc, aggB);  // kills xb; last use of rowptr/esrc
    {
        unsigned short* W2lb2 = (unsigned short*)ws;          // 32 KB (rowptr region, now dead)
        unsigned short* W2rb2 = W2lb2 + 128 * 128;
        cvt_kernel<<<(128 * 128 / 4 + 255) / 256, 256, 0, stream>>>(W2l, W2lb2, 128 * 128 / 4);
        cvt_kernel<<<(128 * 128 / 4 + 255) / 256, 256, 0, stream>>>(W2r, W2rb2, 128 * 128 / 4);
        gemm_mfma_kernel<128, false, false><<<GB, 256, 0, stream>>>(aggB, hb, W2lb2, W2rb2, b2, out);
    }
}

// Round 10
// 327.100 us; speedup vs baseline: 1.1182x; 1.1182x over previous
//
#include <hip/hip_runtime.h>

#define NN 100000
#define NE 1600000
#define SCAN_BLK 2048

#define BSH 9                                  // 512 nodes/bucket
#define NBUCK2 ((NN + 511) / 512)              // 196 coarse buckets
#define CHUNK 8192                             // edges per partition block
#define NCHK ((NE + CHUNK - 1) / CHUNK)        // 196 chunks
#define L2T (NBUCK2 * NCHK)                    // 38416
#define NSTRIP (NN / 32)                       // 3125 exact
#define NSB2 ((L2T + SCAN_BLK - 1) / SCAN_BLK) // 19

using bf16x8 = __attribute__((ext_vector_type(8))) short;
using f32x16 = __attribute__((ext_vector_type(16))) float;

// ---- bf16 helpers (RNE) ----
__device__ __forceinline__ unsigned short f2bf(float f) {
    unsigned u = __float_as_uint(f);
    u += 0x7FFFu + ((u >> 16) & 1u);
    return (unsigned short)(u >> 16);
}
__device__ __forceinline__ float bf2f(unsigned short h) {
    return __uint_as_float(((unsigned)h) << 16);
}

// ---------------- merged prep: hist2 + cvt(x) + cvt(W1l) + cvt(W1r) ----------------
// All four are independent (disjoint outputs, input-only reads); one dispatch
// replaces four. Blocks [0,NCHK): per-chunk bucket histogram (LDS atomics).
// Blocks [NCHK, NCHK+6250): x -> bf16. Last 16 blocks: W1 planes -> bf16.
__global__ __launch_bounds__(256) void prep_kernel(const int* __restrict__ dst,
                                                   int* __restrict__ histm,
                                                   const float* __restrict__ x,
                                                   unsigned short* __restrict__ xb,
                                                   const float* __restrict__ W1l,
                                                   const float* __restrict__ W1r,
                                                   unsigned short* __restrict__ W1lb,
                                                   unsigned short* __restrict__ W1rb) {
    __shared__ int lh[256];
    int blk = blockIdx.x, tid = threadIdx.x;
    if (blk < NCHK) {                           // ---- hist2 ----
        lh[tid] = 0;
        __syncthreads();
        int base = blk * CHUNK;
#pragma unroll
        for (int t = 0; t < CHUNK / 256; t++) {
            int e = base + t * 256 + tid;
            if (e < NE) atomicAdd(&lh[dst[e] >> BSH], 1);
        }
        __syncthreads();
        if (tid < NBUCK2) histm[tid * NCHK + blk] = lh[tid];   // bucket-major
        return;
    }
    blk -= NCHK;
    if (blk < NN * 64 / 4 / 256) {              // ---- cvt x (6250 blocks) ----
        int i = blk * 256 + tid;
        float4 f = ((const float4*)x)[i];
        ((ushort4*)xb)[i] = make_ushort4(f2bf(f.x), f2bf(f.y), f2bf(f.z), f2bf(f.w));
        return;
    }
    blk -= NN * 64 / 4 / 256;
    const int N1 = 128 * 64 / 4;                // 2048 float4 per W1 plane
    int j = blk * 256 + tid;
    const float* in; unsigned short* out;
    if (j < N1) { in = W1l; out = W1lb; }
    else        { j -= N1; if (j >= N1) return; in = W1r; out = W1rb; }
    float4 f = ((const float4*)in)[j];
    ((ushort4*)out)[j] = make_ushort4(f2bf(f.x), f2bf(f.y), f2bf(f.z), f2bf(f.w));
}

// ---------------- exclusive scan, stage 1 ----------------
__global__ __launch_bounds__(256) void scan1_kernel(int* __restrict__ data,
                                                    int* __restrict__ bsums, int L) {
    __shared__ int s[256];
    int bid = blockIdx.x, tid = threadIdx.x;
    int base = bid * SCAN_BLK + tid * 8;
    int v[8];
    int sum = 0;
#pragma unroll
    for (int t = 0; t < 8; t++) {
        int idx = base + t;
        v[t] = (idx < L) ? data[idx] : 0;
        sum += v[t];
    }
    s[tid] = sum;
    __syncthreads();
    for (int off = 1; off < 256; off <<= 1) {
        int val = (tid >= off) ? s[tid - off] : 0;
        __syncthreads();
        s[tid] += val;
        __syncthreads();
    }
    int excl = s[tid] - sum;
    if (tid == 255) bsums[bid] = s[255];
    int run = excl;
#pragma unroll
    for (int t = 0; t < 8; t++) {
        int idx = base + t;
        if (idx < L) data[idx] = run;
        run += v[t];
    }
}

// ---------------- scan stage 2: one wave over n<=64 sums ----------------
__global__ __launch_bounds__(64) void scan2_kernel(int* __restrict__ bsums, int n) {
    int tid = threadIdx.x;
    int orig = (tid < n) ? bsums[tid] : 0;
    int v = orig;
    for (int off = 1; off < 64; off <<= 1) {
        int nb = __shfl_up(v, off, 64);
        if (tid >= off) v += nb;
    }
    if (tid < n) bsums[tid] = v - orig;
}

// ---------------- add offsets (histm) ----------------
__global__ __launch_bounds__(256) void scan_add_kernel(int* __restrict__ data,
                                                       const int* __restrict__ bsums, int L) {
    int i = blockIdx.x * 256 + threadIdx.x;
    if (i < L) data[i] += bsums[i / SCAN_BLK];
}

// ---------------- deterministic coarse scatter (LDS cursors) ----------------
__global__ __launch_bounds__(256) void scatter2_kernel(const int* __restrict__ src,
                                                       const int* __restrict__ dst,
                                                       const int* __restrict__ histm,
                                                       int* __restrict__ tmp) {
    __shared__ int lcur[256];
    int blk = blockIdx.x, tid = threadIdx.x;
    if (tid < NBUCK2) lcur[tid] = histm[tid * NCHK + blk];
    __syncthreads();
    int base = blk * CHUNK;
#pragma unroll
    for (int t = 0; t < CHUNK / 256; t++) {
        int e = base + t * 256 + tid;
        if (e < NE) {
            int d = dst[e];
            int p = atomicAdd(&lcur[d >> BSH], 1);      // LDS atomic
            tmp[p] = src[e] | ((d & 511) << 17);        // src<2^17
        }
    }
}

// ---------------- fused count + scan + place per bucket ----------------
__global__ __launch_bounds__(256) void count_place_kernel(const int* __restrict__ histm,
                                                          const int* __restrict__ tmp,
                                                          int* __restrict__ rowptr,
                                                          int* __restrict__ esrc) {
    __shared__ int cnt[512];   // counts, then cursors
    __shared__ int s[256];
    int b = blockIdx.x, tid = threadIdx.x;
    int beg = histm[b * NCHK];
    int end = (b == NBUCK2 - 1) ? NE : histm[(b + 1) * NCHK];

    cnt[tid] = 0; cnt[tid + 256] = 0;
    __syncthreads();
    for (int e = beg + tid; e < end; e += 256)
        atomicAdd(&cnt[tmp[e] >> 17], 1);               // LDS atomic
    __syncthreads();

    int c0 = cnt[2 * tid], c1 = cnt[2 * tid + 1];
    int sum = c0 + c1;
    s[tid] = sum;
    __syncthreads();
    for (int off = 1; off < 256; off <<= 1) {
        int val = (tid >= off) ? s[tid - off] : 0;
        __syncthreads();
        s[tid] += val;
        __syncthreads();
    }
    int o0 = beg + s[tid] - sum;                        // exclusive
    int o1 = o0 + c0;
    cnt[2 * tid] = o0;                                  // cursors
    cnt[2 * tid + 1] = o1;
    int node0 = (b << BSH) + 2 * tid;
    if (node0 < NN)     rowptr[node0]     = o0;
    if (node0 + 1 < NN) rowptr[node0 + 1] = o1;
    if (b == 0 && tid == 0) rowptr[NN] = NE;
    __syncthreads();

    for (int e = beg + tid; e < end; e += 256) {
        int v = tmp[e];
        int p = atomicAdd(&cnt[v >> 17], 1);            // LDS atomic
        esrc[p] = v & 0x1FFFF;
    }
}

// ---------------- both W2 planes -> bf16, one dispatch ----------------
__global__ __launch_bounds__(256) void cvtw2_kernel(const float* __restrict__ W2l,
                                                    const float* __restrict__ W2r,
                                                    unsigned short* __restrict__ W2lb,
                                                    unsigned short* __restrict__ W2rb) {
    const int N2 = 128 * 128 / 4;               // 4096 float4 per plane
    int j = blockIdx.x * 256 + threadIdx.x;
    const float* in; unsigned short* out;
    if (j < N2) { in = W2l; out = W2lb; }
    else        { j -= N2; if (j >= N2) return; in = W2r; out = W2rb; }
    float4 f = ((const float4*)in)[j];
    ((ushort4*)out)[j] = make_ushort4(f2bf(f.x), f2bf(f.y), f2bf(f.z), f2bf(f.w));
}

// ---------------- bf16 mean-aggregate, K=64 ----------------
// Wave per node. 8 lanes/edge x 16B (bf16x8) = 128B row; 8 edges per load
// instruction; x2 unroll = 16 edges (2KB) in flight; deg~16 -> typical node
// completes the main loop in one iteration.
__global__ __launch_bounds__(256) void agg64_kernel(const unsigned short* __restrict__ feat,
                                                    const int* __restrict__ rowptr,
                                                    const int* __restrict__ esrc,
                                                    unsigned short* __restrict__ agg) {
    int node = blockIdx.x * 4 + (threadIdx.x >> 6);
    int lane = threadIdx.x & 63;
    int es = lane >> 3;            // edge slot 0..7
    int fi = lane & 7;             // feature block (8 bf16)
    int beg = rowptr[node], end = rowptr[node + 1];

    float ax[8];
#pragma unroll
    for (int i = 0; i < 8; i++) ax[i] = 0.0f;

    int e = beg;
    for (; e + 15 < end; e += 16) {
        int sA = esrc[e + es];
        int sB = esrc[e + 8 + es];
        bf16x8 uA = *(const bf16x8*)(feat + (size_t)sA * 64 + fi * 8);
        bf16x8 uB = *(const bf16x8*)(feat + (size_t)sB * 64 + fi * 8);
#pragma unroll
        for (int i = 0; i < 8; i++)
            ax[i] += bf2f((unsigned short)uA[i]) + bf2f((unsigned short)uB[i]);
    }
    if (e + 7 < end) {
        int s = esrc[e + es];
        bf16x8 u = *(const bf16x8*)(feat + (size_t)s * 64 + fi * 8);
#pragma unroll
        for (int i = 0; i < 8; i++) ax[i] += bf2f((unsigned short)u[i]);
        e += 8;
    }
    if (es < end - e) {
        int s = esrc[e + es];
        bf16x8 u = *(const bf16x8*)(feat + (size_t)s * 64 + fi * 8);
#pragma unroll
        for (int i = 0; i < 8; i++) ax[i] += bf2f((unsigned short)u[i]);
    }

#pragma unroll
    for (int i = 0; i < 8; i++) {
        ax[i] += __shfl_xor(ax[i], 8);
        ax[i] += __shfl_xor(ax[i], 16);
        ax[i] += __shfl_xor(ax[i], 32);
    }
    if (es == 0) {
        float inv = 1.0f / fmaxf((float)(end - beg), 1.0f);
        bf16x8 o;
#pragma unroll
        for (int i = 0; i < 8; i++) o[i] = (short)f2bf(ax[i] * inv);
        *(bf16x8*)(agg + (size_t)node * 64 + fi * 8) = o;
    }
}

// ---------------- bf16 mean-aggregate, K=128 ----------------
// Wave per node. 16 lanes/edge x 16B (bf16x8) = 256B row; 4 edges per load
// instruction; 16-edge main iteration = 4x16B loads in flight per lane.
__global__ __launch_bounds__(256) void agg128_kernel(const unsigned short* __restrict__ feat,
                                                     const int* __restrict__ rowptr,
                                                     const int* __restrict__ esrc,
                                                     unsigned short* __restrict__ agg) {
    int node = blockIdx.x * 4 + (threadIdx.x >> 6);
    int lane = threadIdx.x & 63;
    int es = lane >> 4;            // edge slot 0..3
    int fi = lane & 15;            // feature block (8 bf16)
    int beg = rowptr[node], end = rowptr[node + 1];

    float ax[8];
#pragma unroll
    for (int i = 0; i < 8; i++) ax[i] = 0.0f;

    int e = beg;
    for (; e + 15 < end; e += 16) {
        int s0 = esrc[e + es];
        int s1 = esrc[e + 4 + es];
        int s2 = esrc[e + 8 + es];
        int s3 = esrc[e + 12 + es];
        bf16x8 u0 = *(const bf16x8*)(feat + (size_t)s0 * 128 + fi * 8);
        bf16x8 u1 = *(const bf16x8*)(feat + (size_t)s1 * 128 + fi * 8);
        bf16x8 u2 = *(const bf16x8*)(feat + (size_t)s2 * 128 + fi * 8);
        bf16x8 u3 = *(const bf16x8*)(feat + (size_t)s3 * 128 + fi * 8);
#pragma unroll
        for (int i = 0; i < 8; i++)
            ax[i] += (bf2f((unsigned short)u0[i]) + bf2f((unsigned short)u1[i])) +
                     (bf2f((unsigned short)u2[i]) + bf2f((unsigned short)u3[i]));
    }
    for (; e + 3 < end; e += 4) {
        int s = esrc[e + es];
        bf16x8 u = *(const bf16x8*)(feat + (size_t)s * 128 + fi * 8);
#pragma unroll
        for (int i = 0; i < 8; i++) ax[i] += bf2f((unsigned short)u[i]);
    }
    if (es < end - e) {
        int s = esrc[e + es];
        bf16x8 u = *(const bf16x8*)(feat + (size_t)s * 128 + fi * 8);
#pragma unroll
        for (int i = 0; i < 8; i++) ax[i] += bf2f((unsigned short)u[i]);
    }

#pragma unroll
    for (int i = 0; i < 8; i++) {
        ax[i] += __shfl_xor(ax[i], 16);
        ax[i] += __shfl_xor(ax[i], 32);
    }
    if (es == 0) {
        float inv = 1.0f / fmaxf((float)(end - beg), 1.0f);
        bf16x8 o;
#pragma unroll
        for (int i = 0; i < 8; i++) o[i] = (short)f2bf(ax[i] * inv);
        *(bf16x8*)(agg + (size_t)node * 128 + fi * 8) = o;
    }
}

// ---------------- MFMA GEMM: out[n,0:128] = A1@Wa.T + A2@Wb.T + bias ----------------
template <int K, bool RELU, bool OUTBF>
__global__ __launch_bounds__(256) void gemm_mfma_kernel(
    const unsigned short* __restrict__ A1,
    const unsigned short* __restrict__ A2,
    const unsigned short* __restrict__ Wa,
    const unsigned short* __restrict__ Wb,
    const float* __restrict__ bias,
    void* __restrict__ outv) {
    int strip = blockIdx.x * 4 + (threadIdx.x >> 6);
    if (strip >= NSTRIP) return;
    const int lane = threadIdx.x & 63;
    const int m = lane & 31;
    const int half = lane >> 5;
    const int base = strip * 32;

    f32x16 acc[4];
#pragma unroll
    for (int nb = 0; nb < 4; ++nb)
#pragma unroll
        for (int r = 0; r < 16; ++r) acc[nb][r] = 0.0f;

    const unsigned short* ar1 = A1 + (size_t)(base + m) * K + half * 8;
    const unsigned short* ar2 = A2 + (size_t)(base + m) * K + half * 8;
#pragma unroll
    for (int kc = 0; kc < K; kc += 16) {
        bf16x8 a = *(const bf16x8*)(ar1 + kc);
#pragma unroll
        for (int nb = 0; nb < 4; ++nb) {
            bf16x8 b = *(const bf16x8*)(Wa + (size_t)(nb * 32 + m) * K + kc + half * 8);
            acc[nb] = __builtin_amdgcn_mfma_f32_32x32x16_bf16(a, b, acc[nb], 0, 0, 0);
        }
    }
#pragma unroll
    for (int kc = 0; kc < K; kc += 16) {
        bf16x8 a = *(const bf16x8*)(ar2 + kc);
#pragma unroll
        for (int nb = 0; nb < 4; ++nb) {
            bf16x8 b = *(const bf16x8*)(Wb + (size_t)(nb * 32 + m) * K + kc + half * 8);
            acc[nb] = __builtin_amdgcn_mfma_f32_32x32x16_bf16(a, b, acc[nb], 0, 0, 0);
        }
    }

#pragma unroll
    for (int nb = 0; nb < 4; ++nb) {
        int j = nb * 32 + m;
        float bz = bias[j];
#pragma unroll
        for (int r = 0; r < 16; ++r) {
            int row = (r & 3) + 8 * (r >> 2) + 4 * half;
            float v = acc[nb][r] + bz;
            if (RELU) v = fmaxf(v, 0.0f);
            size_t idx = (size_t)(base + row) * 128 + j;
            if (OUTBF) ((unsigned short*)outv)[idx] = f2bf(v);
            else       ((float*)outv)[idx] = v;
        }
    }
}

extern "C" void kernel_launch(void* const* d_in, const int* in_sizes, int n_in,
                              void* d_out, int out_size, void* d_ws, size_t ws_size,
                              hipStream_t stream) {
    const float* x   = (const float*)d_in[0];
    const int*   ei  = (const int*)d_in[1];
    const float* W1l = (const float*)d_in[2];
    const float* W1r = (const float*)d_in[3];
    const float* b1  = (const float*)d_in[4];
    const float* W2l = (const float*)d_in[5];
    const float* W2r = (const float*)d_in[6];
    const float* b2  = (const float*)d_in[7];
    float* out = (float*)d_out;

    const int* src = ei;        // edge_index[0]
    const int* dst = ei + NE;   // edge_index[1]

    // ---- workspace layout (58,003,456 B, proven) ----
    // rowptr/esrc live until agg128; W2 planes converted into the dead
    // rowptr region just before gemm2. W1 planes in d_out (untouched until
    // gemm2 epilogue). E region: tmp/histm/bsums transient, then hb.
    char* ws = (char*)d_ws;
    int* rowptr = (int*)ws;                                  // [0, 401408)
    int* esrc   = (int*)(ws + 401408);                       // NE ints
    unsigned short* aggB = (unsigned short*)(ws + 6803456);  // NN*128 bf16 (25.6 MB)
    unsigned short* xb   = aggB + (size_t)NN * 64;           // NN*64 bf16, aggB upper half
    char* E = ws + 32403456;                                 // 25.6 MB region
    unsigned short* hb = (unsigned short*)E;                 // NN*128 bf16
    int* tmp   = (int*)E;                                    // NE ints (transient)
    int* histm = (int*)(E + 6400000);                        // L2T ints (transient)
    int* bsums = (int*)(E + 6560000);                        // <=64 ints (transient)
    unsigned short* W1lb = (unsigned short*)d_out;           // 128*64 bf16 (16 KB)
    unsigned short* W1rb = W1lb + 128 * 64;

    const int GB = (NSTRIP + 3) / 4;                         // 782 gemm blocks
    const int PREP_BLKS = NCHK + NN * 64 / 4 / 256 + 2 * (128 * 64 / 4 / 256); // 196+6250+16

    // ---- prep (hist2 + cvt x + cvt W1) + CSR build; no global atomics ----
    prep_kernel<<<PREP_BLKS, 256, 0, stream>>>(dst, histm, x, xb, W1l, W1r, W1lb, W1rb);
    scan1_kernel<<<NSB2, 256, 0, stream>>>(histm, bsums, L2T);
    scan2_kernel<<<1, 64, 0, stream>>>(bsums, NSB2);
    scan_add_kernel<<<(L2T + 255) / 256, 256, 0, stream>>>(histm, bsums, L2T);
    scatter2_kernel<<<NCHK, 256, 0, stream>>>(src, dst, histm, tmp);
    count_place_kernel<<<NBUCK2, 256, 0, stream>>>(histm, tmp, rowptr, esrc);

    // ---- layer 1: hb = bf16(relu(mean(agg) @ W1l.T + x @ W1r.T + b1)) ----
    agg64_kernel<<<NN / 4, 256, 0, stream>>>(xb, rowptr, esrc, aggB);
    gemm_mfma_kernel<64, true, true><<<GB, 256, 0, stream>>>(aggB, xb, W1lb, W1rb, b1, hb);

    // ---- layer 2: out = mean(agg2) @ W2l.T + hb @ W2r.T + b2 ----
    agg128_kernel<<<NN / 4, 256, 0, stream>>>(hb, rowptr, esrc, aggB);  // last use of rowptr/esrc
    {
        unsigned short* W2lb = (unsigned short*)ws;           // rowptr region, now dead
        unsigned short* W2rb = W2lb + 128 * 128;
        cvtw2_kernel<<<32, 256, 0, stream>>>(W2l, W2r, W2lb, W2rb);
        gemm_mfma_kernel<128, false, false><<<GB, 256, 0, stream>>>(aggB, hb, W2lb, W2rb, b2, out);
    }
}

// Round 11
// 313.955 us; speedup vs baseline: 1.1650x; 1.0419x over previous
//
#include <hip/hip_runtime.h>

#define NN 100000
#define NE 1600000
#define SCAN_BLK 8192

#define BSH 8                                  // 256 nodes/bucket
#define NBUCK2 ((NN + 255) / 256)              // 391 buckets
#define CHUNK 2048                             // edges per partition block
#define NCHK ((NE + CHUNK - 1) / CHUNK)        // 782 chunks
#define L2T (NBUCK2 * NCHK)                    // 305762
#define NSTRIP (NN / 32)                       // 3125 exact
#define NSB2 ((L2T + SCAN_BLK - 1) / SCAN_BLK) // 38

using bf16x8 = __attribute__((ext_vector_type(8))) short;
using f32x16 = __attribute__((ext_vector_type(16))) float;

// ---- bf16 helpers (RNE) ----
__device__ __forceinline__ unsigned short f2bf(float f) {
    unsigned u = __float_as_uint(f);
    u += 0x7FFFu + ((u >> 16) & 1u);
    return (unsigned short)(u >> 16);
}
__device__ __forceinline__ float bf2f(unsigned short h) {
    return __uint_as_float(((unsigned)h) << 16);
}

// ---------------- merged prep: hist2 + cvt(x) + cvt(W1l) + cvt(W1r) ----------------
// Blocks [0,NCHK): per-chunk bucket histogram (LDS atomics), now 782 blocks
// (3/CU vs the old 196 = <1/CU — the CSR chain was occupancy-starved).
__global__ __launch_bounds__(256) void prep_kernel(const int* __restrict__ dst,
                                                   int* __restrict__ histm,
                                                   const float* __restrict__ x,
                                                   unsigned short* __restrict__ xb,
                                                   const float* __restrict__ W1l,
                                                   const float* __restrict__ W1r,
                                                   unsigned short* __restrict__ W1lb,
                                                   unsigned short* __restrict__ W1rb) {
    __shared__ int lh[NBUCK2];
    int blk = blockIdx.x, tid = threadIdx.x;
    if (blk < NCHK) {                           // ---- hist ----
        for (int i = tid; i < NBUCK2; i += 256) lh[i] = 0;
        __syncthreads();
        int base = blk * CHUNK;
#pragma unroll
        for (int t = 0; t < CHUNK / 256; t++) {
            int e = base + t * 256 + tid;
            if (e < NE) atomicAdd(&lh[dst[e] >> BSH], 1);
        }
        __syncthreads();
        for (int i = tid; i < NBUCK2; i += 256)
            histm[i * NCHK + blk] = lh[i];      // bucket-major
        return;
    }
    blk -= NCHK;
    if (blk < NN * 64 / 4 / 256) {              // ---- cvt x (6250 blocks) ----
        int i = blk * 256 + tid;
        float4 f = ((const float4*)x)[i];
        ((ushort4*)xb)[i] = make_ushort4(f2bf(f.x), f2bf(f.y), f2bf(f.z), f2bf(f.w));
        return;
    }
    blk -= NN * 64 / 4 / 256;
    const int N1 = 128 * 64 / 4;                // 2048 float4 per W1 plane
    int j = blk * 256 + tid;
    const float* in; unsigned short* out;
    if (j < N1) { in = W1l; out = W1lb; }
    else        { j -= N1; if (j >= N1) return; in = W1r; out = W1rb; }
    float4 f = ((const float4*)in)[j];
    ((ushort4*)out)[j] = make_ushort4(f2bf(f.x), f2bf(f.y), f2bf(f.z), f2bf(f.w));
}

// ---------------- exclusive scan, stage 1 (32 elems/thread) ----------------
__global__ __launch_bounds__(256) void scan1_kernel(int* __restrict__ data,
                                                    int* __restrict__ bsums, int L) {
    __shared__ int s[256];
    int bid = blockIdx.x, tid = threadIdx.x;
    int base = bid * SCAN_BLK + tid * 32;
    int v[32];
    int sum = 0;
#pragma unroll
    for (int t = 0; t < 32; t++) {
        int idx = base + t;
        v[t] = (idx < L) ? data[idx] : 0;
        sum += v[t];
    }
    s[tid] = sum;
    __syncthreads();
    for (int off = 1; off < 256; off <<= 1) {
        int val = (tid >= off) ? s[tid - off] : 0;
        __syncthreads();
        s[tid] += val;
        __syncthreads();
    }
    int excl = s[tid] - sum;
    if (tid == 255) bsums[bid] = s[255];
    int run = excl;
#pragma unroll
    for (int t = 0; t < 32; t++) {
        int idx = base + t;
        if (idx < L) data[idx] = run;
        run += v[t];
    }
}

// ---------------- scan stage 2: one wave over n<=64 sums ----------------
__global__ __launch_bounds__(64) void scan2_kernel(int* __restrict__ bsums, int n) {
    int tid = threadIdx.x;
    int orig = (tid < n) ? bsums[tid] : 0;
    int v = orig;
    for (int off = 1; off < 64; off <<= 1) {
        int nb = __shfl_up(v, off, 64);
        if (tid >= off) v += nb;
    }
    if (tid < n) bsums[tid] = v - orig;
}

// ---------------- add offsets (histm) ----------------
__global__ __launch_bounds__(256) void scan_add_kernel(int* __restrict__ data,
                                                       const int* __restrict__ bsums, int L) {
    int i = blockIdx.x * 256 + threadIdx.x;
    if (i < L) data[i] += bsums[i / SCAN_BLK];
}

// ---------------- deterministic coarse scatter (LDS cursors) ----------------
// 782 blocks (3/CU) x 2048 edges.
__global__ __launch_bounds__(256) void scatter2_kernel(const int* __restrict__ src,
                                                       const int* __restrict__ dst,
                                                       const int* __restrict__ histm,
                                                       int* __restrict__ tmp) {
    __shared__ int lcur[NBUCK2];
    int blk = blockIdx.x, tid = threadIdx.x;
    for (int i = tid; i < NBUCK2; i += 256) lcur[i] = histm[i * NCHK + blk];
    __syncthreads();
    int base = blk * CHUNK;
#pragma unroll
    for (int t = 0; t < CHUNK / 256; t++) {
        int e = base + t * 256 + tid;
        if (e < NE) {
            int d = dst[e];
            int p = atomicAdd(&lcur[d >> BSH], 1);      // LDS atomic
            tmp[p] = src[e] | ((d & 255) << 17);        // src<2^17, 8-bit offset
        }
    }
}

// ---------------- fused count + scan + place per bucket ----------------
// 391 blocks x ~4100 edges, 256 nodes/bucket: tid owns one node.
__global__ __launch_bounds__(256) void count_place_kernel(const int* __restrict__ histm,
                                                          const int* __restrict__ tmp,
                                                          int* __restrict__ rowptr,
                                                          int* __restrict__ esrc) {
    __shared__ int cnt[256];   // counts, then cursors
    __shared__ int s[256];
    int b = blockIdx.x, tid = threadIdx.x;
    int beg = histm[b * NCHK];
    int end = (b == NBUCK2 - 1) ? NE : histm[(b + 1) * NCHK];

    cnt[tid] = 0;
    __syncthreads();
    for (int e = beg + tid; e < end; e += 256)
        atomicAdd(&cnt[tmp[e] >> 17], 1);               // LDS atomic
    __syncthreads();

    int c = cnt[tid];
    s[tid] = c;
    __syncthreads();
    for (int off = 1; off < 256; off <<= 1) {
        int val = (tid >= off) ? s[tid - off] : 0;
        __syncthreads();
        s[tid] += val;
        __syncthreads();
    }
    int o = beg + s[tid] - c;                           // exclusive
    cnt[tid] = o;                                       // cursor
    int node = (b << BSH) + tid;
    if (node < NN) rowptr[node] = o;
    if (b == 0 && tid == 0) rowptr[NN] = NE;
    __syncthreads();

    for (int e = beg + tid; e < end; e += 256) {
        int v = tmp[e];
        int p = atomicAdd(&cnt[v >> 17], 1);            // LDS atomic
        esrc[p] = v & 0x1FFFF;
    }
}

// ---------------- both W2 planes -> bf16, one dispatch ----------------
__global__ __launch_bounds__(256) void cvtw2_kernel(const float* __restrict__ W2l,
                                                    const float* __restrict__ W2r,
                                                    unsigned short* __restrict__ W2lb,
                                                    unsigned short* __restrict__ W2rb) {
    const int N2 = 128 * 128 / 4;               // 4096 float4 per plane
    int j = blockIdx.x * 256 + threadIdx.x;
    const float* in; unsigned short* out;
    if (j < N2) { in = W2l; out = W2lb; }
    else        { j -= N2; if (j >= N2) return; in = W2r; out = W2rb; }
    float4 f = ((const float4*)in)[j];
    ((ushort4*)out)[j] = make_ushort4(f2bf(f.x), f2bf(f.y), f2bf(f.z), f2bf(f.w));
}

// ---------------- bf16 mean-aggregate, K=64 ----------------
__global__ __launch_bounds__(256) void agg64_kernel(const unsigned short* __restrict__ feat,
                                                    const int* __restrict__ rowptr,
                                                    const int* __restrict__ esrc,
                                                    unsigned short* __restrict__ agg) {
    int node = blockIdx.x * 4 + (threadIdx.x >> 6);
    int lane = threadIdx.x & 63;
    int es = lane >> 3;            // edge slot 0..7
    int fi = lane & 7;             // feature block (8 bf16)
    int beg = rowptr[node], end = rowptr[node + 1];

    float ax[8];
#pragma unroll
    for (int i = 0; i < 8; i++) ax[i] = 0.0f;

    int e = beg;
    for (; e + 15 < end; e += 16) {
        int sA = esrc[e + es];
        int sB = esrc[e + 8 + es];
        bf16x8 uA = *(const bf16x8*)(feat + (size_t)sA * 64 + fi * 8);
        bf16x8 uB = *(const bf16x8*)(feat + (size_t)sB * 64 + fi * 8);
#pragma unroll
        for (int i = 0; i < 8; i++)
            ax[i] += bf2f((unsigned short)uA[i]) + bf2f((unsigned short)uB[i]);
    }
    if (e + 7 < end) {
        int s = esrc[e + es];
        bf16x8 u = *(const bf16x8*)(feat + (size_t)s * 64 + fi * 8);
#pragma unroll
        for (int i = 0; i < 8; i++) ax[i] += bf2f((unsigned short)u[i]);
        e += 8;
    }
    if (es < end - e) {
        int s = esrc[e + es];
        bf16x8 u = *(const bf16x8*)(feat + (size_t)s * 64 + fi * 8);
#pragma unroll
        for (int i = 0; i < 8; i++) ax[i] += bf2f((unsigned short)u[i]);
    }

#pragma unroll
    for (int i = 0; i < 8; i++) {
        ax[i] += __shfl_xor(ax[i], 8);
        ax[i] += __shfl_xor(ax[i], 16);
        ax[i] += __shfl_xor(ax[i], 32);
    }
    if (es == 0) {
        float inv = 1.0f / fmaxf((float)(end - beg), 1.0f);
        bf16x8 o;
#pragma unroll
        for (int i = 0; i < 8; i++) o[i] = (short)f2bf(ax[i] * inv);
        *(bf16x8*)(agg + (size_t)node * 64 + fi * 8) = o;
    }
}

// ---------------- bf16 mean-aggregate, K=128 ----------------
__global__ __launch_bounds__(256) void agg128_kernel(const unsigned short* __restrict__ feat,
                                                     const int* __restrict__ rowptr,
                                                     const int* __restrict__ esrc,
                                                     unsigned short* __restrict__ agg) {
    int node = blockIdx.x * 4 + (threadIdx.x >> 6);
    int lane = threadIdx.x & 63;
    int es = lane >> 4;            // edge slot 0..3
    int fi = lane & 15;            // feature block (8 bf16)
    int beg = rowptr[node], end = rowptr[node + 1];

    float ax[8];
#pragma unroll
    for (int i = 0; i < 8; i++) ax[i] = 0.0f;

    int e = beg;
    for (; e + 15 < end; e += 16) {
        int s0 = esrc[e + es];
        int s1 = esrc[e + 4 + es];
        int s2 = esrc[e + 8 + es];
        int s3 = esrc[e + 12 + es];
        bf16x8 u0 = *(const bf16x8*)(feat + (size_t)s0 * 128 + fi * 8);
        bf16x8 u1 = *(const bf16x8*)(feat + (size_t)s1 * 128 + fi * 8);
        bf16x8 u2 = *(const bf16x8*)(feat + (size_t)s2 * 128 + fi * 8);
        bf16x8 u3 = *(const bf16x8*)(feat + (size_t)s3 * 128 + fi * 8);
#pragma unroll
        for (int i = 0; i < 8; i++)
            ax[i] += (bf2f((unsigned short)u0[i]) + bf2f((unsigned short)u1[i])) +
                     (bf2f((unsigned short)u2[i]) + bf2f((unsigned short)u3[i]));
    }
    for (; e + 3 < end; e += 4) {
        int s = esrc[e + es];
        bf16x8 u = *(const bf16x8*)(feat + (size_t)s * 128 + fi * 8);
#pragma unroll
        for (int i = 0; i < 8; i++) ax[i] += bf2f((unsigned short)u[i]);
    }
    if (es < end - e) {
        int s = esrc[e + es];
        bf16x8 u = *(const bf16x8*)(feat + (size_t)s * 128 + fi * 8);
#pragma unroll
        for (int i = 0; i < 8; i++) ax[i] += bf2f((unsigned short)u[i]);
    }

#pragma unroll
    for (int i = 0; i < 8; i++) {
        ax[i] += __shfl_xor(ax[i], 16);
        ax[i] += __shfl_xor(ax[i], 32);
    }
    if (es == 0) {
        float inv = 1.0f / fmaxf((float)(end - beg), 1.0f);
        bf16x8 o;
#pragma unroll
        for (int i = 0; i < 8; i++) o[i] = (short)f2bf(ax[i] * inv);
        *(bf16x8*)(agg + (size_t)node * 128 + fi * 8) = o;
    }
}

// ---------------- MFMA GEMM: out[n,0:128] = A1@Wa.T + A2@Wb.T + bias ----------------
template <int K, bool RELU, bool OUTBF>
__global__ __launch_bounds__(256) void gemm_mfma_kernel(
    const unsigned short* __restrict__ A1,
    const unsigned short* __restrict__ A2,
    const unsigned short* __restrict__ Wa,
    const unsigned short* __restrict__ Wb,
    const float* __restrict__ bias,
    void* __restrict__ outv) {
    int strip = blockIdx.x * 4 + (threadIdx.x >> 6);
    if (strip >= NSTRIP) return;
    const int lane = threadIdx.x & 63;
    const int m = lane & 31;
    const int half = lane >> 5;
    const int base = strip * 32;

    f32x16 acc[4];
#pragma unroll
    for (int nb = 0; nb < 4; ++nb)
#pragma unroll
        for (int r = 0; r < 16; ++r) acc[nb][r] = 0.0f;

    const unsigned short* ar1 = A1 + (size_t)(base + m) * K + half * 8;
    const unsigned short* ar2 = A2 + (size_t)(base + m) * K + half * 8;
#pragma unroll
    for (int kc = 0; kc < K; kc += 16) {
        bf16x8 a = *(const bf16x8*)(ar1 + kc);
#pragma unroll
        for (int nb = 0; nb < 4; ++nb) {
            bf16x8 b = *(const bf16x8*)(Wa + (size_t)(nb * 32 + m) * K + kc + half * 8);
            acc[nb] = __builtin_amdgcn_mfma_f32_32x32x16_bf16(a, b, acc[nb], 0, 0, 0);
        }
    }
#pragma unroll
    for (int kc = 0; kc < K; kc += 16) {
        bf16x8 a = *(const bf16x8*)(ar2 + kc);
#pragma unroll
        for (int nb = 0; nb < 4; ++nb) {
            bf16x8 b = *(const bf16x8*)(Wb + (size_t)(nb * 32 + m) * K + kc + half * 8);
            acc[nb] = __builtin_amdgcn_mfma_f32_32x32x16_bf16(a, b, acc[nb], 0, 0, 0);
        }
    }

#pragma unroll
    for (int nb = 0; nb < 4; ++nb) {
        int j = nb * 32 + m;
        float bz = bias[j];
#pragma unroll
        for (int r = 0; r < 16; ++r) {
            int row = (r & 3) + 8 * (r >> 2) + 4 * half;
            float v = acc[nb][r] + bz;
            if (RELU) v = fmaxf(v, 0.0f);
            size_t idx = (size_t)(base + row) * 128 + j;
            if (OUTBF) ((unsigned short*)outv)[idx] = f2bf(v);
            else       ((float*)outv)[idx] = v;
        }
    }
}

extern "C" void kernel_launch(void* const* d_in, const int* in_sizes, int n_in,
                              void* d_out, int out_size, void* d_ws, size_t ws_size,
                              hipStream_t stream) {
    const float* x   = (const float*)d_in[0];
    const int*   ei  = (const int*)d_in[1];
    const float* W1l = (const float*)d_in[2];
    const float* W1r = (const float*)d_in[3];
    const float* b1  = (const float*)d_in[4];
    const float* W2l = (const float*)d_in[5];
    const float* W2r = (const float*)d_in[6];
    const float* b2  = (const float*)d_in[7];
    float* out = (float*)d_out;

    const int* src = ei;        // edge_index[0]
    const int* dst = ei + NE;   // edge_index[1]

    // ---- workspace layout (58,003,456 B, proven) ----
    // rowptr/esrc live until agg128; W2 planes converted into the dead
    // rowptr region just before gemm2. W1 planes in d_out (untouched until
    // gemm2 epilogue). E region: tmp(6.4MB)/histm(1.23MB)/bsums transient,
    // then hb (25.6MB) overwrites after count_place.
    char* ws = (char*)d_ws;
    int* rowptr = (int*)ws;                                  // [0, 401408)
    int* esrc   = (int*)(ws + 401408);                       // NE ints
    unsigned short* aggB = (unsigned short*)(ws + 6803456);  // NN*128 bf16 (25.6 MB)
    unsigned short* xb   = aggB + (size_t)NN * 64;           // NN*64 bf16, aggB upper half
    char* E = ws + 32403456;                                 // 25.6 MB region
    unsigned short* hb = (unsigned short*)E;                 // NN*128 bf16
    int* tmp   = (int*)E;                                    // NE ints (transient)
    int* histm = (int*)(E + 6400000);                        // L2T ints = 1.23 MB (transient)
    int* bsums = (int*)(E + 7700000);                        // <=64 ints (transient)
    unsigned short* W1lb = (unsigned short*)d_out;           // 128*64 bf16 (16 KB)
    unsigned short* W1rb = W1lb + 128 * 64;

    const int GB = (NSTRIP + 3) / 4;                         // 782 gemm blocks
    const int PREP_BLKS = NCHK + NN * 64 / 4 / 256 + 2 * (128 * 64 / 4 / 256); // 782+6250+16

    // ---- prep (hist + cvt x + cvt W1) + CSR build; no global atomics ----
    prep_kernel<<<PREP_BLKS, 256, 0, stream>>>(dst, histm, x, xb, W1l, W1r, W1lb, W1rb);
    scan1_kernel<<<NSB2, 256, 0, stream>>>(histm, bsums, L2T);
    scan2_kernel<<<1, 64, 0, stream>>>(bsums, NSB2);
    scan_add_kernel<<<(L2T + 255) / 256, 256, 0, stream>>>(histm, bsums, L2T);
    scatter2_kernel<<<NCHK, 256, 0, stream>>>(src, dst, histm, tmp);
    count_place_kernel<<<NBUCK2, 256, 0, stream>>>(histm, tmp, rowptr, esrc);

    // ---- layer 1: hb = bf16(relu(mean(agg) @ W1l.T + x @ W1r.T + b1)) ----
    agg64_kernel<<<NN / 4, 256, 0, stream>>>(xb, rowptr, esrc, aggB);
    gemm_mfma_kernel<64, true, true><<<GB, 256, 0, stream>>>(aggB, xb, W1lb, W1rb, b1, hb);

    // ---- layer 2: out = mean(agg2) @ W2l.T + hb @ W2r.T + b2 ----
    agg128_kernel<<<NN / 4, 256, 0, stream>>>(hb, rowptr, esrc, aggB);  // last use of rowptr/esrc
    {
        unsigned short* W2lb = (unsigned short*)ws;           // rowptr region, now dead
        unsigned short* W2rb = W2lb + 128 * 128;
        cvtw2_kernel<<<32, 256, 0, stream>>>(W2l, W2r, W2lb, W2rb);
        gemm_mfma_kernel<128, false, false><<<GB, 256, 0, stream>>>(aggB, hb, W2lb, W2rb, b2, out);
    }
}

// Round 12
// 290.168 us; speedup vs baseline: 1.2605x; 1.0820x over previous
//
#include <hip/hip_runtime.h>

#define NN 100000
#define NE 1600000
#define SCAN_BLK 2048

#define BSH 9                                  // 512 nodes/bucket
#define NBUCK2 ((NN + 511) / 512)              // 196 buckets
#define CHUNK 8192                             // edges per partition block
#define NCHK ((NE + CHUNK - 1) / CHUNK)        // 196 chunks
#define L2T (NBUCK2 * NCHK)                    // 38416
#define NSTRIP (NN / 32)                       // 3125 exact
#define NSB2 ((L2T + SCAN_BLK - 1) / SCAN_BLK) // 19
#define NXF4 (NN * 64 / 4)                     // 1,600,000 float4 in x
#define NXB ((NXF4 + 1023) / 1024)             // 1563 cvt-x blocks

using bf16x8 = __attribute__((ext_vector_type(8))) short;
using f32x16 = __attribute__((ext_vector_type(16))) float;

// ---- bf16 helpers (RNE) ----
__device__ __forceinline__ unsigned short f2bf(float f) {
    unsigned u = __float_as_uint(f);
    u += 0x7FFFu + ((u >> 16) & 1u);
    return (unsigned short)(u >> 16);
}
__device__ __forceinline__ float bf2f(unsigned short h) {
    return __uint_as_float(((unsigned)h) << 16);
}

// ---------------- merged prep: hist + cvt(x) + cvt(W1) at 1024 thr/block ----------------
// Partition geometry back to CHUNK=8192/196 buckets (42-edge = 168B tmp
// segments, the write-coalescing sweet spot from round 6); occupancy fixed
// via 16-wave blocks instead of finer chunks (round 11's +13us came with a
// hidden scatter write-locality loss — this keeps both).
__global__ __launch_bounds__(1024) void prep_kernel(const int* __restrict__ dst,
                                                    int* __restrict__ histm,
                                                    const float* __restrict__ x,
                                                    unsigned short* __restrict__ xb,
                                                    const float* __restrict__ W1l,
                                                    const float* __restrict__ W1r,
                                                    unsigned short* __restrict__ W1lb,
                                                    unsigned short* __restrict__ W1rb) {
    __shared__ int lh[NBUCK2];
    int blk = blockIdx.x, tid = threadIdx.x;
    if (blk < NCHK) {                           // ---- hist ----
        if (tid < NBUCK2) lh[tid] = 0;
        __syncthreads();
        int base = blk * CHUNK;
#pragma unroll
        for (int t = 0; t < CHUNK / 1024; t++) {
            int e = base + t * 1024 + tid;
            if (e < NE) atomicAdd(&lh[dst[e] >> BSH], 1);
        }
        __syncthreads();
        if (tid < NBUCK2) histm[tid * NCHK + blk] = lh[tid];   // bucket-major
        return;
    }
    blk -= NCHK;
    if (blk < NXB) {                            // ---- cvt x ----
        int i = blk * 1024 + tid;
        if (i < NXF4) {
            float4 f = ((const float4*)x)[i];
            ((ushort4*)xb)[i] = make_ushort4(f2bf(f.x), f2bf(f.y), f2bf(f.z), f2bf(f.w));
        }
        return;
    }
    blk -= NXB;                                 // ---- cvt W1 (4 blocks) ----
    const int N1 = 128 * 64 / 4;                // 2048 float4 per plane
    int j = blk * 1024 + tid;
    const float* in; unsigned short* out;
    if (j < N1) { in = W1l; out = W1lb; }
    else        { j -= N1; if (j >= N1) return; in = W1r; out = W1rb; }
    float4 f = ((const float4*)in)[j];
    ((ushort4*)out)[j] = make_ushort4(f2bf(f.x), f2bf(f.y), f2bf(f.z), f2bf(f.w));
}

// ---------------- exclusive scan, stage 1 (8 elems/thread) ----------------
__global__ __launch_bounds__(256) void scan1_kernel(int* __restrict__ data,
                                                    int* __restrict__ bsums, int L) {
    __shared__ int s[256];
    int bid = blockIdx.x, tid = threadIdx.x;
    int base = bid * SCAN_BLK + tid * 8;
    int v[8];
    int sum = 0;
#pragma unroll
    for (int t = 0; t < 8; t++) {
        int idx = base + t;
        v[t] = (idx < L) ? data[idx] : 0;
        sum += v[t];
    }
    s[tid] = sum;
    __syncthreads();
    for (int off = 1; off < 256; off <<= 1) {
        int val = (tid >= off) ? s[tid - off] : 0;
        __syncthreads();
        s[tid] += val;
        __syncthreads();
    }
    int excl = s[tid] - sum;
    if (tid == 255) bsums[bid] = s[255];
    int run = excl;
#pragma unroll
    for (int t = 0; t < 8; t++) {
        int idx = base + t;
        if (idx < L) data[idx] = run;
        run += v[t];
    }
}

// ---------------- scan_add with inline bsums prefix (folds old scan2) ----------------
__global__ __launch_bounds__(256) void scan_add_kernel(int* __restrict__ data,
                                                       const int* __restrict__ bsums, int L) {
    __shared__ int bs[NSB2];
    int tid = threadIdx.x;
    if (tid < NSB2) bs[tid] = bsums[tid];
    __syncthreads();
    int i = blockIdx.x * 256 + tid;
    if (i < L) {
        int b = i / SCAN_BLK;                   // <= 18
        int add = 0;
        for (int k = 0; k < b; k++) add += bs[k];
        data[i] += add;
    }
}

// ---------------- deterministic coarse scatter (LDS cursors, 1024 thr) ----------------
__global__ __launch_bounds__(1024) void scatter2_kernel(const int* __restrict__ src,
                                                        const int* __restrict__ dst,
                                                        const int* __restrict__ histm,
                                                        int* __restrict__ tmp) {
    __shared__ int lcur[NBUCK2];
    int blk = blockIdx.x, tid = threadIdx.x;
    if (tid < NBUCK2) lcur[tid] = histm[tid * NCHK + blk];
    __syncthreads();
    int base = blk * CHUNK;
#pragma unroll
    for (int t = 0; t < CHUNK / 1024; t++) {
        int e = base + t * 1024 + tid;
        if (e < NE) {
            int d = dst[e];
            int p = atomicAdd(&lcur[d >> BSH], 1);      // LDS atomic
            tmp[p] = src[e] | ((d & 511) << 17);        // src<2^17
        }
    }
}

// ---------------- fused count + scan + place per bucket (1024 thr) ----------------
__global__ __launch_bounds__(1024) void count_place_kernel(const int* __restrict__ histm,
                                                           const int* __restrict__ tmp,
                                                           int* __restrict__ rowptr,
                                                           int* __restrict__ esrc) {
    __shared__ int cnt[512];   // counts, then cursors
    __shared__ int s[1024];
    int b = blockIdx.x, tid = threadIdx.x;
    int beg = histm[b * NCHK];
    int end = (b == NBUCK2 - 1) ? NE : histm[(b + 1) * NCHK];

    if (tid < 512) cnt[tid] = 0;
    __syncthreads();
    for (int e = beg + tid; e < end; e += 1024)
        atomicAdd(&cnt[tmp[e] >> 17], 1);               // LDS atomic
    __syncthreads();

    int c = (tid < 512) ? cnt[tid] : 0;
    s[tid] = c;
    __syncthreads();
    for (int off = 1; off < 1024; off <<= 1) {
        int val = (tid >= off) ? s[tid - off] : 0;
        __syncthreads();
        s[tid] += val;
        __syncthreads();
    }
    if (tid < 512) {
        int o = beg + s[tid] - c;                       // exclusive
        cnt[tid] = o;                                   // cursor
        int node = (b << BSH) + tid;
        if (node < NN) rowptr[node] = o;
    }
    if (b == 0 && tid == 0) rowptr[NN] = NE;
    __syncthreads();

    for (int e = beg + tid; e < end; e += 1024) {
        int v = tmp[e];
        int p = atomicAdd(&cnt[v >> 17], 1);            // LDS atomic
        esrc[p] = v & 0x1FFFF;
    }
}

// ---------------- both W2 planes -> bf16, one dispatch ----------------
__global__ __launch_bounds__(256) void cvtw2_kernel(const float* __restrict__ W2l,
                                                    const float* __restrict__ W2r,
                                                    unsigned short* __restrict__ W2lb,
                                                    unsigned short* __restrict__ W2rb) {
    const int N2 = 128 * 128 / 4;               // 4096 float4 per plane
    int j = blockIdx.x * 256 + threadIdx.x;
    const float* in; unsigned short* out;
    if (j < N2) { in = W2l; out = W2lb; }
    else        { j -= N2; if (j >= N2) return; in = W2r; out = W2rb; }
    float4 f = ((const float4*)in)[j];
    ((ushort4*)out)[j] = make_ushort4(f2bf(f.x), f2bf(f.y), f2bf(f.z), f2bf(f.w));
}

// ---------------- bf16 mean-aggregate, K=64 ----------------
__global__ __launch_bounds__(256) void agg64_kernel(const unsigned short* __restrict__ feat,
                                                    const int* __restrict__ rowptr,
                                                    const int* __restrict__ esrc,
                                                    unsigned short* __restrict__ agg) {
    int node = blockIdx.x * 4 + (threadIdx.x >> 6);
    int lane = threadIdx.x & 63;
    int es = lane >> 3;            // edge slot 0..7
    int fi = lane & 7;             // feature block (8 bf16)
    int beg = rowptr[node], end = rowptr[node + 1];

    float ax[8];
#pragma unroll
    for (int i = 0; i < 8; i++) ax[i] = 0.0f;

    int e = beg;
    for (; e + 15 < end; e += 16) {
        int sA = esrc[e + es];
        int sB = esrc[e + 8 + es];
        bf16x8 uA = *(const bf16x8*)(feat + (size_t)sA * 64 + fi * 8);
        bf16x8 uB = *(const bf16x8*)(feat + (size_t)sB * 64 + fi * 8);
#pragma unroll
        for (int i = 0; i < 8; i++)
            ax[i] += bf2f((unsigned short)uA[i]) + bf2f((unsigned short)uB[i]);
    }
    if (e + 7 < end) {
        int s = esrc[e + es];
        bf16x8 u = *(const bf16x8*)(feat + (size_t)s * 64 + fi * 8);
#pragma unroll
        for (int i = 0; i < 8; i++) ax[i] += bf2f((unsigned short)u[i]);
        e += 8;
    }
    if (es < end - e) {
        int s = esrc[e + es];
        bf16x8 u = *(const bf16x8*)(feat + (size_t)s * 64 + fi * 8);
#pragma unroll
        for (int i = 0; i < 8; i++) ax[i] += bf2f((unsigned short)u[i]);
    }

#pragma unroll
    for (int i = 0; i < 8; i++) {
        ax[i] += __shfl_xor(ax[i], 8);
        ax[i] += __shfl_xor(ax[i], 16);
        ax[i] += __shfl_xor(ax[i], 32);
    }
    if (es == 0) {
        float inv = 1.0f / fmaxf((float)(end - beg), 1.0f);
        bf16x8 o;
#pragma unroll
        for (int i = 0; i < 8; i++) o[i] = (short)f2bf(ax[i] * inv);
        *(bf16x8*)(agg + (size_t)node * 64 + fi * 8) = o;
    }
}

// ---------------- bf16 mean-aggregate, K=128 ----------------
__global__ __launch_bounds__(256) void agg128_kernel(const unsigned short* __restrict__ feat,
                                                     const int* __restrict__ rowptr,
                                                     const int* __restrict__ esrc,
                                                     unsigned short* __restrict__ agg) {
    int node = blockIdx.x * 4 + (threadIdx.x >> 6);
    int lane = threadIdx.x & 63;
    int es = lane >> 4;            // edge slot 0..3
    int fi = lane & 15;            // feature block (8 bf16)
    int beg = rowptr[node], end = rowptr[node + 1];

    float ax[8];
#pragma unroll
    for (int i = 0; i < 8; i++) ax[i] = 0.0f;

    int e = beg;
    for (; e + 15 < end; e += 16) {
        int s0 = esrc[e + es];
        int s1 = esrc[e + 4 + es];
        int s2 = esrc[e + 8 + es];
        int s3 = esrc[e + 12 + es];
        bf16x8 u0 = *(const bf16x8*)(feat + (size_t)s0 * 128 + fi * 8);
        bf16x8 u1 = *(const bf16x8*)(feat + (size_t)s1 * 128 + fi * 8);
        bf16x8 u2 = *(const bf16x8*)(feat + (size_t)s2 * 128 + fi * 8);
        bf16x8 u3 = *(const bf16x8*)(feat + (size_t)s3 * 128 + fi * 8);
#pragma unroll
        for (int i = 0; i < 8; i++)
            ax[i] += (bf2f((unsigned short)u0[i]) + bf2f((unsigned short)u1[i])) +
                     (bf2f((unsigned short)u2[i]) + bf2f((unsigned short)u3[i]));
    }
    for (; e + 3 < end; e += 4) {
        int s = esrc[e + es];
        bf16x8 u = *(const bf16x8*)(feat + (size_t)s * 128 + fi * 8);
#pragma unroll
        for (int i = 0; i < 8; i++) ax[i] += bf2f((unsigned short)u[i]);
    }
    if (es < end - e) {
        int s = esrc[e + es];
        bf16x8 u = *(const bf16x8*)(feat + (size_t)s * 128 + fi * 8);
#pragma unroll
        for (int i = 0; i < 8; i++) ax[i] += bf2f((unsigned short)u[i]);
    }

#pragma unroll
    for (int i = 0; i < 8; i++) {
        ax[i] += __shfl_xor(ax[i], 16);
        ax[i] += __shfl_xor(ax[i], 32);
    }
    if (es == 0) {
        float inv = 1.0f / fmaxf((float)(end - beg), 1.0f);
        bf16x8 o;
#pragma unroll
        for (int i = 0; i < 8; i++) o[i] = (short)f2bf(ax[i] * inv);
        *(bf16x8*)(agg + (size_t)node * 128 + fi * 8) = o;
    }
}

// ---------------- MFMA GEMM: out[n,0:128] = A1@Wa.T + A2@Wb.T + bias ----------------
template <int K, bool RELU, bool OUTBF>
__global__ __launch_bounds__(256) void gemm_mfma_kernel(
    const unsigned short* __restrict__ A1,
    const unsigned short* __restrict__ A2,
    const unsigned short* __restrict__ Wa,
    const unsigned short* __restrict__ Wb,
    const float* __restrict__ bias,
    void* __restrict__ outv) {
    int strip = blockIdx.x * 4 + (threadIdx.x >> 6);
    if (strip >= NSTRIP) return;
    const int lane = threadIdx.x & 63;
    const int m = lane & 31;
    const int half = lane >> 5;
    const int base = strip * 32;

    f32x16 acc[4];
#pragma unroll
    for (int nb = 0; nb < 4; ++nb)
#pragma unroll
        for (int r = 0; r < 16; ++r) acc[nb][r] = 0.0f;

    const unsigned short* ar1 = A1 + (size_t)(base + m) * K + half * 8;
    const unsigned short* ar2 = A2 + (size_t)(base + m) * K + half * 8;
#pragma unroll
    for (int kc = 0; kc < K; kc += 16) {
        bf16x8 a = *(const bf16x8*)(ar1 + kc);
#pragma unroll
        for (int nb = 0; nb < 4; ++nb) {
            bf16x8 b = *(const bf16x8*)(Wa + (size_t)(nb * 32 + m) * K + kc + half * 8);
            acc[nb] = __builtin_amdgcn_mfma_f32_32x32x16_bf16(a, b, acc[nb], 0, 0, 0);
        }
    }
#pragma unroll
    for (int kc = 0; kc < K; kc += 16) {
        bf16x8 a = *(const bf16x8*)(ar2 + kc);
#pragma unroll
        for (int nb = 0; nb < 4; ++nb) {
            bf16x8 b = *(const bf16x8*)(Wb + (size_t)(nb * 32 + m) * K + kc + half * 8);
            acc[nb] = __builtin_amdgcn_mfma_f32_32x32x16_bf16(a, b, acc[nb], 0, 0, 0);
        }
    }

#pragma unroll
    for (int nb = 0; nb < 4; ++nb) {
        int j = nb * 32 + m;
        float bz = bias[j];
#pragma unroll
        for (int r = 0; r < 16; ++r) {
            int row = (r & 3) + 8 * (r >> 2) + 4 * half;
            float v = acc[nb][r] + bz;
            if (RELU) v = fmaxf(v, 0.0f);
            size_t idx = (size_t)(base + row) * 128 + j;
            if (OUTBF) ((unsigned short*)outv)[idx] = f2bf(v);
            else       ((float*)outv)[idx] = v;
        }
    }
}

extern "C" void kernel_launch(void* const* d_in, const int* in_sizes, int n_in,
                              void* d_out, int out_size, void* d_ws, size_t ws_size,
                              hipStream_t stream) {
    const float* x   = (const float*)d_in[0];
    const int*   ei  = (const int*)d_in[1];
    const float* W1l = (const float*)d_in[2];
    const float* W1r = (const float*)d_in[3];
    const float* b1  = (const float*)d_in[4];
    const float* W2l = (const float*)d_in[5];
    const float* W2r = (const float*)d_in[6];
    const float* b2  = (const float*)d_in[7];
    float* out = (float*)d_out;

    const int* src = ei;        // edge_index[0]
    const int* dst = ei + NE;   // edge_index[1]

    // ---- workspace layout (58,003,456 B, proven) ----
    char* ws = (char*)d_ws;
    int* rowptr = (int*)ws;                                  // [0, 401408)
    int* esrc   = (int*)(ws + 401408);                       // NE ints
    unsigned short* aggB = (unsigned short*)(ws + 6803456);  // NN*128 bf16 (25.6 MB)
    unsigned short* xb   = aggB + (size_t)NN * 64;           // NN*64 bf16, aggB upper half
    char* E = ws + 32403456;                                 // 25.6 MB region
    unsigned short* hb = (unsigned short*)E;                 // NN*128 bf16
    int* tmp   = (int*)E;                                    // NE ints (transient)
    int* histm = (int*)(E + 6400000);                        // L2T ints (transient)
    int* bsums = (int*)(E + 6560000);                        // <=64 ints (transient)
    unsigned short* W1lb = (unsigned short*)d_out;           // 128*64 bf16 (16 KB)
    unsigned short* W1rb = W1lb + 128 * 64;

    const int GB = (NSTRIP + 3) / 4;                         // 782 gemm blocks
    const int PREP_BLKS = NCHK + NXB + 4;                    // 196+1563+4

    // ---- prep (hist + cvt x + cvt W1) + CSR build; no global atomics ----
    prep_kernel<<<PREP_BLKS, 1024, 0, stream>>>(dst, histm, x, xb, W1l, W1r, W1lb, W1rb);
    scan1_kernel<<<NSB2, 256, 0, stream>>>(histm, bsums, L2T);
    scan_add_kernel<<<(L2T + 255) / 256, 256, 0, stream>>>(histm, bsums, L2T);
    scatter2_kernel<<<NCHK, 1024, 0, stream>>>(src, dst, histm, tmp);
    count_place_kernel<<<NBUCK2, 1024, 0, stream>>>(histm, tmp, rowptr, esrc);

    // ---- layer 1: hb = bf16(relu(mean(agg) @ W1l.T + x @ W1r.T + b1)) ----
    agg64_kernel<<<NN / 4, 256, 0, stream>>>(xb, rowptr, esrc, aggB);
    gemm_mfma_kernel<64, true, true><<<GB, 256, 0, stream>>>(aggB, xb, W1lb, W1rb, b1, hb);

    // ---- layer 2: out = mean(agg2) @ W2l.T + hb @ W2r.T + b2 ----
    agg128_kernel<<<NN / 4, 256, 0, stream>>>(hb, rowptr, esrc, aggB);  // last use of rowptr/esrc
    {
        unsigned short* W2lb = (unsigned short*)ws;           // rowptr region, now dead
        unsigned short* W2rb = W2lb + 128 * 128;
        cvtw2_kernel<<<32, 256, 0, stream>>>(W2l, W2r, W2lb, W2rb);
        gemm_mfma_kernel<128, false, false><<<GB, 256, 0, stream>>>(aggB, hb, W2lb, W2rb, b2, out);
    }
}